// Round 17
// baseline (4794.359 us; speedup 1.0000x reference)
//
#include <hip/hip_runtime.h>
#include <hip/hip_bf16.h>
#include <math.h>

typedef unsigned short u16;
typedef __attribute__((ext_vector_type(8))) short bf16x8;
typedef __attribute__((ext_vector_type(4))) float f32x4;
typedef __attribute__((ext_vector_type(16))) float f32x16;

#define IN_CH   256
#define STATE   384
#define OUT_SEQ 32
#define B_SZ    8
#define SEQ     512
#define M_ROWS  4096
#define NJ      768   // 2*STATE

// plane sizes (elements)
#define PS_WB  (NJ*IN_CH)      // 196608
#define PS_WC  (IN_CH*NJ)      // 196608
#define PS_WD  (IN_CH*IN_CH)   // 65536
#define PS_Z   ((size_t)M_ROWS*NJ)
#define PS_X   ((size_t)M_ROWS*IN_CH)

// ---------------- workspace layout (bytes) ----------------
static constexpr size_t B_U   = 0;                                   // P partial
static constexpr size_t B_Z   = B_U  + 8*(size_t)M_ROWS*IN_CH*4;
static constexpr size_t B_XA  = B_Z  + 3*(size_t)M_ROWS*NJ*2;
static constexpr size_t B_XB  = B_XA + 3*(size_t)M_ROWS*IN_CH*2;
static constexpr size_t B_WB  = B_XB + 3*(size_t)M_ROWS*IN_CH*2;
static constexpr size_t B_WC  = B_WB + 3*(size_t)PS_WB*2;
static constexpr size_t B_WD  = B_WC + 3*(size_t)PS_WC*2;
static constexpr size_t B_LAM = B_WD + 3*(size_t)PS_WD*2;            // lam, lam16
static constexpr size_t B_HC  = B_LAM + 2*768*4;                     // Hc0, Hc1
static constexpr size_t B_CNT = B_HC  + 2*(size_t)B_SZ*NJ*4;         // sync counter

// ---------------- helpers ----------------
__device__ __forceinline__ u16 f2b(float v) {
    __hip_bfloat16 h = __float2bfloat16(v);
    return *(u16*)&h;
}
__device__ __forceinline__ float b2f(u16 u) {
    __hip_bfloat16 h = *(__hip_bfloat16*)&u;
    return __bfloat162float(h);
}
__device__ __forceinline__ void split3(float v, u16& a, u16& b, u16& c) {
    a = f2b(v);  float r1 = v  - b2f(a);
    b = f2b(r1); float r2 = r1 - b2f(b);
    c = f2b(r2);
}

// A-fragment-ordered (32x32-family) plane index: element (row, k), NKC = K/32.
__device__ __forceinline__ size_t a_idx(int row, int k, int NKC) {
    return ((size_t)(((row >> 5)*NKC + (k >> 5))*2 + ((k >> 4) & 1))*2 + ((k >> 3) & 1))*256
           + (size_t)(row & 31)*8 + (k & 7);
}

// fragment-index decode for weight prep: r -> (t32,h,hi5,lo5,e)
__device__ __forceinline__ void frag_decode(int r, int& t32, int& h, int& hi5,
                                            int& lo5, int& e) {
    t32 = r >> 10; int r2 = r & 1023;
    h = r2 >> 9;   int r3 = r2 & 511;
    hi5 = r3 >> 8; int r4 = r3 & 255;
    lo5 = r4 >> 3; e = r4 & 7;
}

// grid-wide sync: monotonic counter; RELEASE arrive, RELAXED poll (no cache
// inv per poll -- the R8 lesson), single ACQUIRE after.
__device__ __forceinline__ void gsync(int* cnt, int step) {
    __syncthreads();
    if (threadIdx.x == 0) {
        __hip_atomic_fetch_add(cnt, 1, __ATOMIC_RELEASE, __HIP_MEMORY_SCOPE_AGENT);
        while (__hip_atomic_load(cnt, __ATOMIC_RELAXED, __HIP_MEMORY_SCOPE_AGENT)
               < step*256)
            __builtin_amdgcn_s_sleep(8);
        (void)__hip_atomic_load(cnt, __ATOMIC_ACQUIRE, __HIP_MEMORY_SCOPE_AGENT);
    }
    __syncthreads();
}

// ---------------- prep kernels ----------------
__global__ void prep_lam_hc(const float* __restrict__ nu_log,
                            const float* __restrict__ th_log,
                            float* __restrict__ lam, float* __restrict__ lam16,
                            float* __restrict__ hc0, int* __restrict__ cnt) {
    int n = threadIdx.x;
    if (n == 0) *cnt = 0;
    if (n < STATE) {
        float lm = expf(-expf(nu_log[n]));
        float th = expf(th_log[n]);
        float ar = lm * cosf(th), ai = lm * sinf(th);
        lam[2*n] = ar; lam[2*n+1] = ai;
        float pr = ar, pi = ai;
#pragma unroll
        for (int i = 0; i < 4; ++i) {   // lambda^16
            float nr = pr*pr - pi*pi, ni = 2.f*pr*pi;
            pr = nr; pi = ni;
        }
        lam16[2*n] = pr; lam16[2*n+1] = pi;
    }
    for (int i = threadIdx.x; i < B_SZ*NJ; i += blockDim.x) hc0[i] = 0.f;
}

// fused big prep: WB | WC | WD | X   (total 1507328 = 5888*256 exactly)
__global__ void prep_big(const float* __restrict__ B_re, const float* __restrict__ B_im,
                         const float* __restrict__ gamma_log,
                         const float* __restrict__ C_re, const float* __restrict__ C_im,
                         const float* __restrict__ D, const float* __restrict__ x,
                         u16* __restrict__ W, u16* __restrict__ WC, u16* __restrict__ WD,
                         u16* __restrict__ X1, u16* __restrict__ X2, u16* __restrict__ X3) {
    int idx = blockIdx.x*blockDim.x + threadIdx.x;
    if (idx < PS_WB) {
        int c32 = idx >> 13, r = idx & 8191;
        int t32,h,hi5,lo5,e; frag_decode(r, t32,h,hi5,lo5,e);
        int j = c32*32 + lo5;
        int k = t32*32 + (2*h + hi5)*8 + e;
        int n = j >> 1;
        float g = expf(gamma_log[n]);
        float v = g * ((j & 1) ? B_im[n*IN_CH + k] : B_re[n*IN_CH + k]);
        u16 a,b,cc; split3(v,a,b,cc);
        W[idx] = a; W[idx + PS_WB] = b; W[idx + 2*PS_WB] = cc;
        return;
    }
    idx -= PS_WB;
    if (idx < PS_WC) {
        int c32 = idx / 24576, r = idx % 24576;
        int t32,h,hi5,lo5,e; frag_decode(r, t32,h,hi5,lo5,e);
        int o = c32*32 + lo5;
        int j = t32*32 + (2*h + hi5)*8 + e;
        int n = j >> 1;
        float v = (j & 1) ? -C_im[o*STATE + n] : C_re[o*STATE + n];
        u16 a,b,c; split3(v,a,b,c);
        WC[idx] = a; WC[idx + PS_WC] = b; WC[idx + 2*PS_WC] = c;
        return;
    }
    idx -= PS_WC;
    if (idx < PS_WD) {
        int c32 = idx >> 13, r = idx & 8191;
        int t32,h,hi5,lo5,e; frag_decode(r, t32,h,hi5,lo5,e);
        int o = c32*32 + lo5;
        int c = t32*32 + (2*h + hi5)*8 + e;
        float v = D[o*IN_CH + c];
        u16 a,b,cc; split3(v,a,b,cc);
        WD[idx] = a; WD[idx + PS_WD] = b; WD[idx + 2*PS_WD] = cc;
        return;
    }
    idx -= PS_WD;
    {
        int row = idx >> 8, k = idx & 255;
        u16 a,b,c; split3(x[idx],a,b,c);
        size_t o = a_idx(row, k, 8);
        X1[o] = a; X2[o] = b; X3[o] = c;
    }
}

// product order for bf16x3 (large terms first)
__device__ __constant__ const int cPI[6] = {0,0,1,0,1,2};
__device__ __constant__ const int cPJ[6] = {0,1,0,2,1,0};

// ---------------- MONO: all 32 iterations in one dispatch -------------------
// grid 256 x 512thr, 1 block/CU. Per iter: F phase (192 front-jobs + 64 WD
// jobs) -> gsync -> G phase (256 gemm2 tiles) -> gsync.
struct MP {
    const u16 *XA1, *XA2, *XA3;
    u16 *XB1, *XB2, *XB3;     // non-const: both are written across iters
    u16 *YA1, *YA2, *YA3;     // aliases: YA = XA writable
    const u16 *WB, *WC, *WD;
    u16 *Z1, *Z2, *Z3;
    float *P;
    const float *lam, *lam16;
    float2 *Hc0, *Hc1;
    float *outp;
    int *cnt;
};

__global__ __launch_bounds__(512, 2)
void mono_k(MP g) {
    __shared__ __align__(16) float Ls[512*34];     // 69.6KB (F: U tile; G: Lred)
    __shared__ float2 car[32][16];
    __shared__ float2 hp[32][16];
    const int tid = threadIdx.x, lane = tid & 63, w = tid >> 6;
    const int bid = blockIdx.x;
    const int l15 = lane & 15, q = lane >> 4;
    const int hb = q >> 1, hi5q = q & 1;
    const int hi5 = lane >> 5, lo5 = lane & 31;
    int step = 0;

    for (int it = 0; it < OUT_SEQ; ++it) {
        const u16* Xc[3]; u16* Xn[3];
        if (it & 1) {
            Xc[0]=g.XB1; Xc[1]=g.XB2; Xc[2]=g.XB3;
            Xn[0]=g.YA1; Xn[1]=g.YA2; Xn[2]=g.YA3;
        } else {
            Xc[0]=g.XA1; Xc[1]=g.XA2; Xc[2]=g.XA3;
            Xn[0]=g.XB1; Xn[1]=g.XB2; Xn[2]=g.XB3;
        }
        const float2* Hin  = (it & 1) ? g.Hc1 : g.Hc0;
        float2*       Hout = (it & 1) ? g.Hc0 : g.Hc1;

        // ================= F phase =================
        if (bid >= 192) {
            // WD job: P = X*WD^T, rows XCD-aligned
            const int k0 = bid - 192;
            const int mt = (k0 & 7)*8 + (k0 >> 3);
            const int wr = w & 1, wc = w >> 1;
            const int m32 = mt*2 + wr;
            f32x16 acc[2];
#pragma unroll
            for (int cj = 0; cj < 2; ++cj)
#pragma unroll
                for (int i = 0; i < 16; ++i) acc[cj][i] = 0.f;

            bf16x8 av[2][3][2], bv[2][2][3][2];
            auto loadA = [&](int buf, int kc) {
#pragma unroll
                for (int p = 0; p < 3; ++p)
#pragma unroll
                    for (int h = 0; h < 2; ++h)
                        av[buf][p][h] = *(const bf16x8*)(Xc[p]
                            + ((((size_t)(m32*8 + kc)*2 + h)*2 + hi5) << 8) + lo5*8);
            };
            auto loadB = [&](int buf, int kc) {
#pragma unroll
                for (int cj = 0; cj < 2; ++cj)
#pragma unroll
                    for (int p = 0; p < 3; ++p)
#pragma unroll
                        for (int h = 0; h < 2; ++h)
                            bv[buf][cj][p][h] = *(const bf16x8*)(g.WD + (size_t)p*PS_WD
                                + ((((size_t)((wc*2 + cj)*8 + kc)*2 + h)*2 + hi5) << 8) + lo5*8);
            };
            loadA(0, 0); loadB(0, 0);
            loadA(1, 1); loadB(1, 1);
#pragma unroll
            for (int kc = 0; kc < 8; ++kc) {
                const int cb = kc & 1;
#pragma unroll
                for (int t6 = 0; t6 < 6; ++t6)
#pragma unroll
                    for (int cj = 0; cj < 2; ++cj)
#pragma unroll
                        for (int h = 0; h < 2; ++h)
                            acc[cj] = __builtin_amdgcn_mfma_f32_32x32x16_bf16(
                                av[cb][cPI[t6]][h], bv[cb][cj][cPJ[t6]][h], acc[cj], 0, 0, 0);
                if (kc + 2 < 8) { loadA(cb, kc + 2); loadB(cb, kc + 2); }
            }
#pragma unroll
            for (int cj = 0; cj < 2; ++cj)
#pragma unroll
                for (int reg = 0; reg < 16; ++reg) {
                    int row = mt*64 + wr*32 + (reg & 3) + 8*(reg >> 2) + 4*hi5;
                    int col = wc*64 + cj*32 + lo5;
                    g.P[(size_t)row*IN_CH + col] = acc[cj][reg];
                }
        } else {
            // front job
            const int b = bid & 7, jt = bid >> 3;

            f32x4 acc[4][2];
#pragma unroll
            for (int i = 0; i < 4; ++i)
#pragma unroll
                for (int n16 = 0; n16 < 2; ++n16) acc[i][n16] = 0.f;

            bf16x8 av[2][4][3], bv[2][2][3];
            auto loadA = [&](int buf, int kc) {
#pragma unroll
                for (int p = 0; p < 3; ++p)
#pragma unroll
                    for (int i = 0; i < 4; ++i) {
                        int m16 = i*8 + w;
                        int row32 = b*16 + (m16 >> 1);
                        int rin = ((m16 & 1) << 4) + l15;
                        av[buf][i][p] = *(const bf16x8*)(Xc[p]
                            + ((((size_t)(row32*8 + kc)*2 + hb)*2 + hi5q) << 8) + rin*8);
                    }
            };
            auto loadB = [&](int buf, int kc) {
#pragma unroll
                for (int p = 0; p < 3; ++p)
#pragma unroll
                    for (int n16 = 0; n16 < 2; ++n16)
                        bv[buf][n16][p] = *(const bf16x8*)(g.WB + (size_t)p*PS_WB
                            + ((((size_t)(jt*8 + kc)*2 + hb)*2 + hi5q) << 8) + (n16*16 + l15)*8);
            };

            loadA(0, 0); loadB(0, 0);
            loadA(1, 1); loadB(1, 1);
#pragma unroll
            for (int kc = 0; kc < 8; ++kc) {
                const int cb = kc & 1;
#pragma unroll
                for (int t6 = 0; t6 < 6; ++t6)
#pragma unroll
                    for (int i = 0; i < 4; ++i)
#pragma unroll
                        for (int n16 = 0; n16 < 2; ++n16)
                            acc[i][n16] = __builtin_amdgcn_mfma_f32_16x16x32_bf16(
                                av[cb][i][cPI[t6]], bv[cb][n16][cPJ[t6]], acc[i][n16], 0, 0, 0);
                if (kc + 2 < 8) { loadA(cb, kc + 2); loadB(cb, kc + 2); }
            }

            // deposit U tile to LDS
#pragma unroll
            for (int i = 0; i < 4; ++i) {
                int m16 = i*8 + w;
#pragma unroll
                for (int n16 = 0; n16 < 2; ++n16)
#pragma unroll
                    for (int r = 0; r < 4; ++r) {
                        int s = m16*16 + q*4 + r;
                        int jl = n16*16 + l15;
                        Ls[s*34 + jl] = acc[i][n16][r];
                    }
            }
            __syncthreads();

            // pass 1: chunk-local scan, local h in place
            {
                int st = tid & 15, ch = tid >> 4;
                int n = jt*16 + st;
                float lre = g.lam[2*n], lim = g.lam[2*n+1];
                float hr = 0.f, hm = 0.f;
#pragma unroll
                for (int t = 0; t < 16; ++t) {
                    int s = ch*16 + t;
                    float2 u = *(const float2*)&Ls[s*34 + 2*st];
                    float nr = fmaf(lre, hr, fmaf(-lim, hm, u.x));
                    float nm = fmaf(lre, hm, fmaf( lim, hr, u.y));
                    hr = nr; hm = nm;
                    *(float2*)&Ls[s*34 + 2*st] = make_float2(hr, hm);
                }
                car[ch][st] = make_float2(hr, hm);
            }
            __syncthreads();

            // parallel prefix over 32 chunks (complex affine), all waves
            {
                int st2 = 2*w + hi5, ch2 = lane & 31;
                int n = jt*16 + st2;
                float2 e = car[ch2][st2];
                float Ar = g.lam16[2*n], Ai = g.lam16[2*n+1];
                float Br = e.x, Bi = e.y;
#pragma unroll
                for (int d = 1; d < 32; d <<= 1) {
                    int src = (lane & 32) | ((lane - d) & 31);
                    float pAr = __shfl(Ar, src), pAi = __shfl(Ai, src);
                    float pBr = __shfl(Br, src), pBi = __shfl(Bi, src);
                    if (ch2 >= d) {
                        float nAr = Ar*pAr - Ai*pAi;
                        float nAi = Ar*pAi + Ai*pAr;
                        float nBr = fmaf(Ar, pBr, fmaf(-Ai, pBi, Br));
                        float nBi = fmaf(Ar, pBi, fmaf( Ai, pBr, Bi));
                        Ar = nAr; Ai = nAi; Br = nBr; Bi = nBi;
                    }
                }
                float2 s0 = Hin[(size_t)b*STATE + n];
                if (ch2 == 31) {
                    float fr = fmaf(Ar, s0.x, fmaf(-Ai, s0.y, Br));
                    float fi = fmaf(Ar, s0.y, fmaf( Ai, s0.x, Bi));
                    Hout[(size_t)b*STATE + n] = make_float2(fr, fi);
                }
                int srcp = (lane & 32) | ((lane - 1) & 31);
                float eAr = __shfl(Ar, srcp), eAi = __shfl(Ai, srcp);
                float eBr = __shfl(Br, srcp), eBi = __shfl(Bi, srcp);
                float sr, si;
                if (ch2 == 0) { sr = s0.x; si = s0.y; }
                else {
                    sr = fmaf(eAr, s0.x, fmaf(-eAi, s0.y, eBr));
                    si = fmaf(eAr, s0.y, fmaf( eAi, s0.x, eBi));
                }
                hp[ch2][st2] = make_float2(sr, si);
            }
            __syncthreads();

            // pass 2: h_t = local_t + lambda^{t+1}*hp; split3; emit
            {
                int st = tid & 15, ch = tid >> 4;
                int n = jt*16 + st;
                float lre = g.lam[2*n], lim = g.lam[2*n+1];
                float2 hh = hp[ch][st];
                float lpr = lre, lpi = lim;
                int j0 = jt*32 + 2*st;
#pragma unroll
                for (int t = 0; t < 16; ++t) {
                    int s = ch*16 + t;
                    float2 hl = *(const float2*)&Ls[s*34 + 2*st];
                    float vr = fmaf(lpr, hh.x, fmaf(-lpi, hh.y, hl.x));
                    float vi = fmaf(lpr, hh.y, fmaf( lpi, hh.x, hl.y));
                    float nlr = lpr*lre - lpi*lim;
                    float nli = lpr*lim + lpi*lre;
                    lpr = nlr; lpi = nli;
                    u16 a1,a2,a3, c1,c2,c3;
                    split3(vr, a1,a2,a3);
                    split3(vi, c1,c2,c3);
                    size_t zo = a_idx(b*512 + s, j0, 24);
                    ushort2 t2;
                    t2.x = a1; t2.y = c1; *(ushort2*)(g.Z1 + zo) = t2;
                    t2.x = a2; t2.y = c2; *(ushort2*)(g.Z2 + zo) = t2;
                    t2.x = a3; t2.y = c3; *(ushort2*)(g.Z3 + zo) = t2;
                }
            }
        }

        gsync(g.cnt, ++step);

        // ================= G phase: gemm2 tile =================
        {
            const int b = bid & 7, mloc = (bid >> 3) & 7, n_t = bid >> 6;
            const int mtile = b*8 + mloc;
            const int m0 = mtile*64, n0 = n_t*64;
            const int kg = w >> 2, wq = w & 3;
            const int wr = wq & 1, wcq = wq >> 1;
            const int c32 = n_t*2 + wcq;
            const int m32 = mtile*2 + wr;
            const int cbase = kg*12;
            float* Lred = Ls;                      // 16KB reuse

            f32x16 accv;
#pragma unroll
            for (int i = 0; i < 16; ++i) accv[i] = 0.f;

            auto aptr = [&](int p, int c, int h) -> const u16* {
                const u16* Zp = (p == 0) ? g.Z1 : (p == 1) ? g.Z2 : g.Z3;
                return Zp + ((((size_t)(m32*24 + c)*2 + h)*2 + hi5) << 8) + lo5*8;
            };
            auto bptr = [&](int p, int c, int h) -> const u16* {
                return g.WC + (size_t)p*PS_WC
                       + ((((size_t)(c32*24 + c)*2 + h)*2 + hi5) << 8) + lo5*8;
            };

            bf16x8 av[2][3][2], bv[2][3][2];
            auto loadA = [&](int buf, int t) {
#pragma unroll
                for (int p = 0; p < 3; ++p)
#pragma unroll
                    for (int h = 0; h < 2; ++h)
                        av[buf][p][h] = *(const bf16x8*)aptr(p, cbase + t, h);
            };
            auto loadB = [&](int buf, int t) {
#pragma unroll
                for (int p = 0; p < 3; ++p)
#pragma unroll
                    for (int h = 0; h < 2; ++h)
                        bv[buf][p][h] = *(const bf16x8*)bptr(p, cbase + t, h);
            };

            loadA(0, 0); loadB(0, 0);
            loadA(1, 1); loadB(1, 1);
#pragma unroll
            for (int t = 0; t < 12; ++t) {
                const int cb = t & 1;
#pragma unroll
                for (int t6 = 0; t6 < 6; ++t6)
                    accv = __builtin_amdgcn_mfma_f32_32x32x16_bf16(
                        av[cb][cPI[t6]][0], bv[cb][cPJ[t6]][0],
                        __builtin_amdgcn_mfma_f32_32x32x16_bf16(
                            av[cb][cPI[t6]][1], bv[cb][cPJ[t6]][1], accv, 0, 0, 0),
                        0, 0, 0);
                if (t + 2 < 12) { loadA(cb, t + 2); loadB(cb, t + 2); }
            }

            __syncthreads();                       // Ls free (F done in this block)
            if (kg == 1) {
#pragma unroll
                for (int reg = 0; reg < 16; ++reg) {
                    int rl = wr*32 + (reg & 3) + 8*(reg >> 2) + 4*hi5;
                    int cl = wcq*32 + lo5;
                    Lred[rl*64 + cl] = accv[reg];
                }
            }
            __syncthreads();
            if (kg == 0) {
#pragma unroll
                for (int reg = 0; reg < 16; ++reg) {
                    int rl = wr*32 + (reg & 3) + 8*(reg >> 2) + 4*hi5;
                    int cl = wcq*32 + lo5;
                    int row = m0 + rl, col = n0 + cl;
                    float v = accv[reg] + Lred[rl*64 + cl]
                            + g.P[(size_t)row*IN_CH + col];
                    u16 a,b2,c; split3(v, a,b2,c);
                    size_t o = a_idx(row, col, 8);
                    Xn[0][o] = a; Xn[1][o] = b2; Xn[2][o] = c;
                    if ((row & (SEQ-1)) == SEQ-1)
                        g.outp[(size_t)((row >> 9)*OUT_SEQ + it)*IN_CH + col] = v;
                }
            }
        }

        if (it + 1 < OUT_SEQ) gsync(g.cnt, ++step);
    }
}

// ---------------- launch ----------------
extern "C" void kernel_launch(void* const* d_in, const int* in_sizes, int n_in,
                              void* d_out, int out_size, void* d_ws, size_t ws_size,
                              hipStream_t stream) {
    const float* x_in      = (const float*)d_in[0];
    const float* nu_log    = (const float*)d_in[1];
    const float* theta_log = (const float*)d_in[2];
    const float* gamma_log = (const float*)d_in[3];
    const float* B_re      = (const float*)d_in[4];
    const float* B_im      = (const float*)d_in[5];
    const float* C_re      = (const float*)d_in[6];
    const float* C_im      = (const float*)d_in[7];
    const float* D         = (const float*)d_in[8];
    float* out = (float*)d_out;

    char* ws = (char*)d_ws;
    float* P = (float*)(ws + B_U);
    u16* Z1 = (u16*)(ws + B_Z);
    u16* Z2 = Z1 + PS_Z;
    u16* Z3 = Z2 + PS_Z;
    u16* XA1 = (u16*)(ws + B_XA);
    u16* XA2 = XA1 + PS_X;
    u16* XA3 = XA2 + PS_X;
    u16* XB1 = (u16*)(ws + B_XB);
    u16* XB2 = XB1 + PS_X;
    u16* XB3 = XB2 + PS_X;
    u16* WB  = (u16*)(ws + B_WB);
    u16* WCt = (u16*)(ws + B_WC);
    u16* WDt = (u16*)(ws + B_WD);
    float* lam   = (float*)(ws + B_LAM);
    float* lam16 = lam + 768;
    float2* Hc0  = (float2*)(ws + B_HC);
    float2* Hc1  = Hc0 + (size_t)B_SZ*STATE;
    int* cnt = (int*)(ws + B_CNT);

    prep_lam_hc<<<1, 384, 0, stream>>>(nu_log, theta_log, lam, lam16, (float*)Hc0, cnt);
    prep_big<<<5888, 256, 0, stream>>>(B_re, B_im, gamma_log, C_re, C_im, D, x_in,
                                       WB, WCt, WDt, XA1, XA2, XA3);

    MP g;
    g.XA1 = XA1; g.XA2 = XA2; g.XA3 = XA3;
    g.XB1 = XB1; g.XB2 = XB2; g.XB3 = XB3;
    g.YA1 = XA1; g.YA2 = XA2; g.YA3 = XA3;
    g.WB = WB; g.WC = WCt; g.WD = WDt;
    g.Z1 = Z1; g.Z2 = Z2; g.Z3 = Z3;
    g.P = P; g.lam = lam; g.lam16 = lam16;
    g.Hc0 = Hc0; g.Hc1 = Hc1;
    g.outp = out; g.cnt = cnt;
    mono_k<<<256, 512, 0, stream>>>(g);
}

// Round 18
// 1271.718 us; speedup vs baseline: 3.7700x; 3.7700x over previous
//
#include <hip/hip_runtime.h>
#include <hip/hip_bf16.h>
#include <math.h>

typedef unsigned short u16;
typedef __attribute__((ext_vector_type(8))) short bf16x8;
typedef __attribute__((ext_vector_type(4))) float f32x4;
typedef __attribute__((ext_vector_type(16))) float f32x16;

#define IN_CH   256
#define STATE   384
#define OUT_SEQ 32
#define B_SZ    8
#define SEQ     512
#define M_ROWS  4096
#define NJ      768   // 2*STATE

// plane sizes (elements)
#define PS_WB  (NJ*IN_CH)      // 196608
#define PS_WC  (IN_CH*NJ)      // 196608
#define PS_WD  (IN_CH*IN_CH)   // 65536
#define PS_Z   ((size_t)M_ROWS*NJ)
#define PS_X   ((size_t)M_ROWS*IN_CH)

// ---------------- workspace layout (bytes) ----------------
static constexpr size_t B_U   = 0;                                   // P partial
static constexpr size_t B_Z   = B_U  + 8*(size_t)M_ROWS*IN_CH*4;
static constexpr size_t B_XA  = B_Z  + 3*(size_t)M_ROWS*NJ*2;
static constexpr size_t B_XB  = B_XA + 3*(size_t)M_ROWS*IN_CH*2;
static constexpr size_t B_WB  = B_XB + 3*(size_t)M_ROWS*IN_CH*2;
static constexpr size_t B_WC  = B_WB + 3*(size_t)PS_WB*2;
static constexpr size_t B_WD  = B_WC + 3*(size_t)PS_WC*2;
static constexpr size_t B_LAM = B_WD + 3*(size_t)PS_WD*2;            // lam, lam16
static constexpr size_t B_HC  = B_LAM + 2*768*4;                     // Hc0, Hc1

// ---------------- helpers ----------------
__device__ __forceinline__ u16 f2b(float v) {
    __hip_bfloat16 h = __float2bfloat16(v);
    return *(u16*)&h;
}
__device__ __forceinline__ float b2f(u16 u) {
    __hip_bfloat16 h = *(__hip_bfloat16*)&u;
    return __bfloat162float(h);
}
__device__ __forceinline__ void split3(float v, u16& a, u16& b, u16& c) {
    a = f2b(v);  float r1 = v  - b2f(a);
    b = f2b(r1); float r2 = r1 - b2f(b);
    c = f2b(r2);
}

// A-fragment-ordered (32x32-family) plane index: element (row, k), NKC = K/32.
__device__ __forceinline__ size_t a_idx(int row, int k, int NKC) {
    return ((size_t)(((row >> 5)*NKC + (k >> 5))*2 + ((k >> 4) & 1))*2 + ((k >> 3) & 1))*256
           + (size_t)(row & 31)*8 + (k & 7);
}

// fragment-index decode for weight prep: r -> (t32,h,hi5,lo5,e)
__device__ __forceinline__ void frag_decode(int r, int& t32, int& h, int& hi5,
                                            int& lo5, int& e) {
    t32 = r >> 10; int r2 = r & 1023;
    h = r2 >> 9;   int r3 = r2 & 511;
    hi5 = r3 >> 8; int r4 = r3 & 255;
    lo5 = r4 >> 3; e = r4 & 7;
}

// ---------------- prep kernels ----------------
__global__ void prep_lam_hc(const float* __restrict__ nu_log,
                            const float* __restrict__ th_log,
                            float* __restrict__ lam, float* __restrict__ lam16,
                            float* __restrict__ hc0) {
    int n = threadIdx.x;
    if (n < STATE) {
        float lm = expf(-expf(nu_log[n]));
        float th = expf(th_log[n]);
        float ar = lm * cosf(th), ai = lm * sinf(th);
        lam[2*n] = ar; lam[2*n+1] = ai;
        float pr = ar, pi = ai;
#pragma unroll
        for (int i = 0; i < 4; ++i) {   // lambda^16
            float nr = pr*pr - pi*pi, ni = 2.f*pr*pi;
            pr = nr; pi = ni;
        }
        lam16[2*n] = pr; lam16[2*n+1] = pi;
    }
    for (int i = threadIdx.x; i < B_SZ*NJ; i += blockDim.x) hc0[i] = 0.f;
}

// fused big prep: WB | WC | WD | X   (total 1507328 = 5888*256 exactly)
__global__ void prep_big(const float* __restrict__ B_re, const float* __restrict__ B_im,
                         const float* __restrict__ gamma_log,
                         const float* __restrict__ C_re, const float* __restrict__ C_im,
                         const float* __restrict__ D, const float* __restrict__ x,
                         u16* __restrict__ W, u16* __restrict__ WC, u16* __restrict__ WD,
                         u16* __restrict__ X1, u16* __restrict__ X2, u16* __restrict__ X3) {
    int idx = blockIdx.x*blockDim.x + threadIdx.x;
    if (idx < PS_WB) {
        int c32 = idx >> 13, r = idx & 8191;
        int t32,h,hi5,lo5,e; frag_decode(r, t32,h,hi5,lo5,e);
        int j = c32*32 + lo5;
        int k = t32*32 + (2*h + hi5)*8 + e;
        int n = j >> 1;
        float g = expf(gamma_log[n]);
        float v = g * ((j & 1) ? B_im[n*IN_CH + k] : B_re[n*IN_CH + k]);
        u16 a,b,cc; split3(v,a,b,cc);
        W[idx] = a; W[idx + PS_WB] = b; W[idx + 2*PS_WB] = cc;
        return;
    }
    idx -= PS_WB;
    if (idx < PS_WC) {
        int c32 = idx / 24576, r = idx % 24576;
        int t32,h,hi5,lo5,e; frag_decode(r, t32,h,hi5,lo5,e);
        int o = c32*32 + lo5;
        int j = t32*32 + (2*h + hi5)*8 + e;
        int n = j >> 1;
        float v = (j & 1) ? -C_im[o*STATE + n] : C_re[o*STATE + n];
        u16 a,b,c; split3(v,a,b,c);
        WC[idx] = a; WC[idx + PS_WC] = b; WC[idx + 2*PS_WC] = c;
        return;
    }
    idx -= PS_WC;
    if (idx < PS_WD) {
        int c32 = idx >> 13, r = idx & 8191;
        int t32,h,hi5,lo5,e; frag_decode(r, t32,h,hi5,lo5,e);
        int o = c32*32 + lo5;
        int c = t32*32 + (2*h + hi5)*8 + e;
        float v = D[o*IN_CH + c];
        u16 a,b,cc; split3(v,a,b,cc);
        WD[idx] = a; WD[idx + PS_WD] = b; WD[idx + 2*PS_WD] = cc;
        return;
    }
    idx -= PS_WD;
    {
        int row = idx >> 8, k = idx & 255;
        u16 a,b,c; split3(x[idx],a,b,c);
        size_t o = a_idx(row, k, 8);
        X1[o] = a; X2[o] = b; X3[o] = c;
    }
}

// product order for bf16x3 (large terms first)
__device__ __constant__ const int cPI[6] = {0,0,1,0,1,2};
__device__ __constant__ const int cPJ[6] = {0,1,0,2,1,0};

// ---------------- FRONT: blocks 0..191: U (LDS) + scan + Z emit; blocks
// 192..255: P = X*WD^T partial (fp32, XCD-aligned rows). 512 threads.
// [R16 structure — known good]
struct G1P { const u16* A[3]; };

__global__ __launch_bounds__(512, 2)
void front_k(G1P ga, const u16* __restrict__ WBp, const u16* __restrict__ WDp,
             u16* __restrict__ Z1, u16* __restrict__ Z2, u16* __restrict__ Z3,
             float* __restrict__ P,
             const float* __restrict__ lam, const float* __restrict__ lam16,
             const float2* __restrict__ HcIn, float2* __restrict__ HcOut) {
    __shared__ __align__(16) float Ls[512*34];     // 69.6KB U tile (front job)
    __shared__ float2 car[32][16];
    __shared__ float2 hp[32][16];
    const int tid = threadIdx.x, lane = tid & 63, w = tid >> 6;
    const int l15 = lane & 15, q = lane >> 4;
    const int hb = q >> 1, hi5q = q & 1;
    const int hi5 = lane >> 5, lo5 = lane & 31;

    if (blockIdx.x >= 192) {
        // ---------- WD job: rows XCD-aligned: mt = (k&7)*8 + (k>>3) ----------
        const int k0 = blockIdx.x - 192;          // 0..63
        const int mt = (k0 & 7)*8 + (k0 >> 3);
        const int wr = w & 1, wc = w >> 1;        // wc 0..3 -> cols wc*64
        const int m32 = mt*2 + wr;
        f32x16 acc[2];
#pragma unroll
        for (int cj = 0; cj < 2; ++cj)
#pragma unroll
            for (int i = 0; i < 16; ++i) acc[cj][i] = 0.f;

        bf16x8 av[2][3][2], bv[2][2][3][2];
        auto loadA = [&](int buf, int kc) {
#pragma unroll
            for (int p = 0; p < 3; ++p)
#pragma unroll
                for (int h = 0; h < 2; ++h)
                    av[buf][p][h] = *(const bf16x8*)(ga.A[p]
                        + ((((size_t)(m32*8 + kc)*2 + h)*2 + hi5) << 8) + lo5*8);
        };
        auto loadB = [&](int buf, int kc) {
#pragma unroll
            for (int cj = 0; cj < 2; ++cj)
#pragma unroll
                for (int p = 0; p < 3; ++p)
#pragma unroll
                    for (int h = 0; h < 2; ++h)
                        bv[buf][cj][p][h] = *(const bf16x8*)(WDp + (size_t)p*PS_WD
                            + ((((size_t)((wc*2 + cj)*8 + kc)*2 + h)*2 + hi5) << 8) + lo5*8);
        };
        loadA(0, 0); loadB(0, 0);
        loadA(1, 1); loadB(1, 1);
#pragma unroll
        for (int kc = 0; kc < 8; ++kc) {
            const int cb = kc & 1;
#pragma unroll
            for (int t6 = 0; t6 < 6; ++t6)
#pragma unroll
                for (int cj = 0; cj < 2; ++cj)
#pragma unroll
                    for (int h = 0; h < 2; ++h)
                        acc[cj] = __builtin_amdgcn_mfma_f32_32x32x16_bf16(
                            av[cb][cPI[t6]][h], bv[cb][cj][cPJ[t6]][h], acc[cj], 0, 0, 0);
            if (kc + 2 < 8) { loadA(cb, kc + 2); loadB(cb, kc + 2); }
        }
#pragma unroll
        for (int cj = 0; cj < 2; ++cj)
#pragma unroll
            for (int reg = 0; reg < 16; ++reg) {
                int row = mt*64 + wr*32 + (reg & 3) + 8*(reg >> 2) + 4*hi5;
                int col = wc*64 + cj*32 + lo5;
                P[(size_t)row*IN_CH + col] = acc[cj][reg];
            }
        return;
    }

    // ---------- front job ----------
    const int b = blockIdx.x & 7, jt = blockIdx.x >> 3;   // XCD-local b

    f32x4 acc[4][2];
#pragma unroll
    for (int i = 0; i < 4; ++i)
#pragma unroll
        for (int n16 = 0; n16 < 2; ++n16) acc[i][n16] = 0.f;

    bf16x8 av[2][4][3], bv[2][2][3];
    auto loadA = [&](int buf, int kc) {
#pragma unroll
        for (int p = 0; p < 3; ++p)
#pragma unroll
            for (int i = 0; i < 4; ++i) {
                int m16 = i*8 + w;
                int row32 = b*16 + (m16 >> 1);
                int rin = ((m16 & 1) << 4) + l15;
                av[buf][i][p] = *(const bf16x8*)(ga.A[p]
                    + ((((size_t)(row32*8 + kc)*2 + hb)*2 + hi5q) << 8) + rin*8);
            }
    };
    auto loadB = [&](int buf, int kc) {
#pragma unroll
        for (int p = 0; p < 3; ++p)
#pragma unroll
            for (int n16 = 0; n16 < 2; ++n16)
                bv[buf][n16][p] = *(const bf16x8*)(WBp + (size_t)p*PS_WB
                    + ((((size_t)(jt*8 + kc)*2 + hb)*2 + hi5q) << 8) + (n16*16 + l15)*8);
    };

    loadA(0, 0); loadB(0, 0);
    loadA(1, 1); loadB(1, 1);
#pragma unroll
    for (int kc = 0; kc < 8; ++kc) {
        const int cb = kc & 1;
#pragma unroll
        for (int t6 = 0; t6 < 6; ++t6)
#pragma unroll
            for (int i = 0; i < 4; ++i)
#pragma unroll
                for (int n16 = 0; n16 < 2; ++n16)
                    acc[i][n16] = __builtin_amdgcn_mfma_f32_16x16x32_bf16(
                        av[cb][i][cPI[t6]], bv[cb][n16][cPJ[t6]], acc[i][n16], 0, 0, 0);
        if (kc + 2 < 8) { loadA(cb, kc + 2); loadB(cb, kc + 2); }
    }

    // deposit U tile to LDS. D-layout (16x16): col=l15, row=q*4+r
#pragma unroll
    for (int i = 0; i < 4; ++i) {
        int m16 = i*8 + w;
#pragma unroll
        for (int n16 = 0; n16 < 2; ++n16)
#pragma unroll
            for (int r = 0; r < 4; ++r) {
                int s = m16*16 + q*4 + r;
                int jl = n16*16 + l15;
                Ls[s*34 + jl] = acc[i][n16][r];
            }
    }
    __syncthreads();

    // pass 1: chunk-local scan from 0; stores local h IN PLACE (over u)
    {
        int st = tid & 15, ch = tid >> 4;
        int n = jt*16 + st;
        float lre = lam[2*n], lim = lam[2*n+1];
        float hr = 0.f, hm = 0.f;
#pragma unroll
        for (int t = 0; t < 16; ++t) {
            int s = ch*16 + t;
            float2 u = *(const float2*)&Ls[s*34 + 2*st];
            float nr = fmaf(lre, hr, fmaf(-lim, hm, u.x));
            float nm = fmaf(lre, hm, fmaf( lim, hr, u.y));
            hr = nr; hm = nm;
            *(float2*)&Ls[s*34 + 2*st] = make_float2(hr, hm);
        }
        car[ch][st] = make_float2(hr, hm);
    }
    __syncthreads();

    // parallel prefix over 32 chunks (complex affine maps), all waves.
    {
        int st2 = 2*w + hi5, ch2 = lane & 31;
        int n = jt*16 + st2;
        float2 e = car[ch2][st2];
        float Ar = lam16[2*n], Ai = lam16[2*n+1];
        float Br = e.x, Bi = e.y;
#pragma unroll
        for (int d = 1; d < 32; d <<= 1) {
            int src = (lane & 32) | ((lane - d) & 31);
            float pAr = __shfl(Ar, src), pAi = __shfl(Ai, src);
            float pBr = __shfl(Br, src), pBi = __shfl(Bi, src);
            if (ch2 >= d) {
                float nAr = Ar*pAr - Ai*pAi;
                float nAi = Ar*pAi + Ai*pAr;
                float nBr = fmaf(Ar, pBr, fmaf(-Ai, pBi, Br));
                float nBi = fmaf(Ar, pBi, fmaf( Ai, pBr, Bi));
                Ar = nAr; Ai = nAi; Br = nBr; Bi = nBi;
            }
        }
        float2 s0 = HcIn[(size_t)b*STATE + n];
        if (ch2 == 31) {
            float fr = fmaf(Ar, s0.x, fmaf(-Ai, s0.y, Br));
            float fi = fmaf(Ar, s0.y, fmaf( Ai, s0.x, Bi));
            HcOut[(size_t)b*STATE + n] = make_float2(fr, fi);
        }
        int srcp = (lane & 32) | ((lane - 1) & 31);
        float eAr = __shfl(Ar, srcp), eAi = __shfl(Ai, srcp);
        float eBr = __shfl(Br, srcp), eBi = __shfl(Bi, srcp);
        float sr, si;
        if (ch2 == 0) { sr = s0.x; si = s0.y; }
        else {
            sr = fmaf(eAr, s0.x, fmaf(-eAi, s0.y, eBr));
            si = fmaf(eAr, s0.y, fmaf( eAi, s0.x, eBi));
        }
        hp[ch2][st2] = make_float2(sr, si);
    }
    __syncthreads();

    // pass 2: elementwise h_t = local_t + lambda^{t+1}*hp; split3; emit
    {
        int st = tid & 15, ch = tid >> 4;
        int n = jt*16 + st;
        float lre = lam[2*n], lim = lam[2*n+1];
        float2 hh = hp[ch][st];
        float lpr = lre, lpi = lim;                 // lambda^{1}
        int j0 = jt*32 + 2*st;
#pragma unroll
        for (int t = 0; t < 16; ++t) {
            int s = ch*16 + t;
            float2 hl = *(const float2*)&Ls[s*34 + 2*st];
            float vr = fmaf(lpr, hh.x, fmaf(-lpi, hh.y, hl.x));
            float vi = fmaf(lpr, hh.y, fmaf( lpi, hh.x, hl.y));
            float nlr = lpr*lre - lpi*lim;
            float nli = lpr*lim + lpi*lre;
            lpr = nlr; lpi = nli;
            u16 a1,a2,a3, c1,c2,c3;
            split3(vr, a1,a2,a3);
            split3(vi, c1,c2,c3);
            size_t zo = a_idx(b*512 + s, j0, 24);
            ushort2 t2;
            t2.x = a1; t2.y = c1; *(ushort2*)(Z1 + zo) = t2;
            t2.x = a2; t2.y = c2; *(ushort2*)(Z2 + zo) = t2;
            t2.x = a3; t2.y = c3; *(ushort2*)(Z3 + zo) = t2;
        }
    }
}

// ---------------- GEMM2: Z*WC^T (K=768) + Lred + P; grid 512 XCD-aligned,
// 256 threads (4 waves: kg x2, wcq x2), 32x64 tile -> up to 3 blocks/CU.
struct G2P {
    const u16* Z[3]; const u16* WC; const float* P;
    u16* O1; u16* O2; u16* O3; float* outp; int iter;
};

__global__ __launch_bounds__(256, 3)
void gemm2_k(G2P g) {
    __shared__ __align__(16) float Lred[2*1024];   // 8KB: [wcq][32*32]
    const int tid = threadIdx.x, lane = tid & 63, w = tid >> 6;   // w 0..3
    const int kg = w >> 1, wcq = w & 1;
    const int bid = blockIdx.x;
    const int b = bid & 7, mloc = (bid >> 3) & 15, n_t = bid >> 7;
    const int m32 = b*16 + mloc;                   // 32-row group
    const int m0 = m32*32, n0 = n_t*64;
    const int hi5 = lane >> 5, lo5 = lane & 31;
    const int c32 = n_t*2 + wcq;
    const int cbase = kg*12;

    f32x16 accv;
#pragma unroll
    for (int i = 0; i < 16; ++i) accv[i] = 0.f;

    auto aptr = [&](int p, int c, int h) -> const u16* {
        return g.Z[p] + ((((size_t)(m32*24 + c)*2 + h)*2 + hi5) << 8) + lo5*8;
    };
    auto bptr = [&](int p, int c, int h) -> const u16* {
        return g.WC + (size_t)p*PS_WC
               + ((((size_t)(c32*24 + c)*2 + h)*2 + hi5) << 8) + lo5*8;
    };

    bf16x8 av[2][3][2], bv[2][3][2];
    auto loadA = [&](int buf, int t) {
#pragma unroll
        for (int p = 0; p < 3; ++p)
#pragma unroll
            for (int h = 0; h < 2; ++h)
                av[buf][p][h] = *(const bf16x8*)aptr(p, cbase + t, h);
    };
    auto loadB = [&](int buf, int t) {
#pragma unroll
        for (int p = 0; p < 3; ++p)
#pragma unroll
            for (int h = 0; h < 2; ++h)
                bv[buf][p][h] = *(const bf16x8*)bptr(p, cbase + t, h);
    };

    loadA(0, 0); loadB(0, 0);
    loadA(1, 1); loadB(1, 1);
#pragma unroll
    for (int t = 0; t < 12; ++t) {
        const int cb = t & 1;
#pragma unroll
        for (int t6 = 0; t6 < 6; ++t6)
            accv = __builtin_amdgcn_mfma_f32_32x32x16_bf16(
                av[cb][cPI[t6]][0], bv[cb][cPJ[t6]][0],
                __builtin_amdgcn_mfma_f32_32x32x16_bf16(
                    av[cb][cPI[t6]][1], bv[cb][cPJ[t6]][1], accv, 0, 0, 0),
                0, 0, 0);
        if (t + 2 < 12) { loadA(cb, t + 2); loadB(cb, t + 2); }
    }

    // kg=1 waves deposit partials; kg=0 waves sum + P + epilogue
    if (kg == 1) {
        float* Lp = Lred + (size_t)wcq*1024;
#pragma unroll
        for (int reg = 0; reg < 16; ++reg) {
            int rl = (reg & 3) + 8*(reg >> 2) + 4*hi5;
            Lp[rl*32 + lo5] = accv[reg];
        }
    }
    __syncthreads();
    if (kg == 0) {
        const float* Lp = Lred + (size_t)wcq*1024;
#pragma unroll
        for (int reg = 0; reg < 16; ++reg) {
            int rl = (reg & 3) + 8*(reg >> 2) + 4*hi5;
            int row = m0 + rl;
            int col = n0 + wcq*32 + lo5;
            float v = accv[reg] + Lp[rl*32 + lo5]
                    + g.P[(size_t)row*IN_CH + col];
            u16 a,b2,c; split3(v, a,b2,c);
            size_t o = a_idx(row, col, 8);
            g.O1[o] = a; g.O2[o] = b2; g.O3[o] = c;
            if ((row & (SEQ-1)) == SEQ-1)
                g.outp[(size_t)((row >> 9)*OUT_SEQ + g.iter)*IN_CH + col] = v;
        }
    }
}

// ---------------- launch ----------------
extern "C" void kernel_launch(void* const* d_in, const int* in_sizes, int n_in,
                              void* d_out, int out_size, void* d_ws, size_t ws_size,
                              hipStream_t stream) {
    const float* x_in      = (const float*)d_in[0];
    const float* nu_log    = (const float*)d_in[1];
    const float* theta_log = (const float*)d_in[2];
    const float* gamma_log = (const float*)d_in[3];
    const float* B_re      = (const float*)d_in[4];
    const float* B_im      = (const float*)d_in[5];
    const float* C_re      = (const float*)d_in[6];
    const float* C_im      = (const float*)d_in[7];
    const float* D         = (const float*)d_in[8];
    float* out = (float*)d_out;

    char* ws = (char*)d_ws;
    float* P = (float*)(ws + B_U);                 // [4096][256] fp32 partial
    u16* Z1 = (u16*)(ws + B_Z);
    u16* Z2 = Z1 + PS_Z;
    u16* Z3 = Z2 + PS_Z;
    u16* XA1 = (u16*)(ws + B_XA);
    u16* XA2 = XA1 + PS_X;
    u16* XA3 = XA2 + PS_X;
    u16* XB1 = (u16*)(ws + B_XB);
    u16* XB2 = XB1 + PS_X;
    u16* XB3 = XB2 + PS_X;
    u16* WB  = (u16*)(ws + B_WB);
    u16* WCt = (u16*)(ws + B_WC);
    u16* WDt = (u16*)(ws + B_WD);
    float* lam   = (float*)(ws + B_LAM);
    float* lam16 = lam + 768;
    float2* Hc0  = (float2*)(ws + B_HC);
    float2* Hc1  = Hc0 + (size_t)B_SZ*STATE;

    prep_lam_hc<<<1, 384, 0, stream>>>(nu_log, theta_log, lam, lam16, (float*)Hc0);
    prep_big<<<5888, 256, 0, stream>>>(B_re, B_im, gamma_log, C_re, C_im, D, x_in,
                                       WB, WCt, WDt, XA1, XA2, XA3);

    for (int it = 0; it < OUT_SEQ; ++it) {
        u16* Xc[3]; u16* Xn[3];
        if (it & 1) { Xc[0]=XB1; Xc[1]=XB2; Xc[2]=XB3; Xn[0]=XA1; Xn[1]=XA2; Xn[2]=XA3; }
        else        { Xc[0]=XA1; Xc[1]=XA2; Xc[2]=XA3; Xn[0]=XB1; Xn[1]=XB2; Xn[2]=XB3; }
        float2* Hin  = (it & 1) ? Hc1 : Hc0;
        float2* Hout = (it & 1) ? Hc0 : Hc1;

        // FRONT: U+scan+Z emit (192 blocks) and P = X*WD^T (64 blocks)
        G1P g1;
        for (int p = 0; p < 3; ++p) g1.A[p] = Xc[p];
        front_k<<<256, 512, 0, stream>>>(
            g1, WB, WDt, Z1, Z2, Z3, P, lam, lam16, Hin, Hout);

        // GEMM2: Z*WC^T (K=768) + Lred + P -> Xn frags + out (512 small blocks)
        G2P g2;
        g2.Z[0]=Z1; g2.Z[1]=Z2; g2.Z[2]=Z3;
        g2.WC = WCt; g2.P = P;
        g2.O1 = Xn[0]; g2.O2 = Xn[1]; g2.O3 = Xn[2];
        g2.outp = out; g2.iter = it;
        gemm2_k<<<512, 256, 0, stream>>>(g2);
    }
}

// Round 20
// 1245.331 us; speedup vs baseline: 3.8499x; 1.0212x over previous
//
#include <hip/hip_runtime.h>
#include <hip/hip_bf16.h>
#include <math.h>

typedef unsigned short u16;
typedef __attribute__((ext_vector_type(8))) short bf16x8;
typedef __attribute__((ext_vector_type(4))) float f32x4;
typedef __attribute__((ext_vector_type(16))) float f32x16;

#define IN_CH   256
#define STATE   384
#define OUT_SEQ 32
#define B_SZ    8
#define SEQ     512
#define M_ROWS  4096
#define NJ      768   // 2*STATE

// plane sizes (elements)
#define PS_WB  (NJ*IN_CH)      // 196608
#define PS_WC  (IN_CH*NJ)      // 196608
#define PS_WD  (IN_CH*IN_CH)   // 65536
#define PS_Z   ((size_t)M_ROWS*NJ)
#define PS_X   ((size_t)M_ROWS*IN_CH)

// ---------------- workspace layout (bytes) ----------------
static constexpr size_t B_U   = 0;                                   // P partial
static constexpr size_t B_Z   = B_U  + 8*(size_t)M_ROWS*IN_CH*4;
static constexpr size_t B_XA  = B_Z  + 3*(size_t)M_ROWS*NJ*2;
static constexpr size_t B_XB  = B_XA + 3*(size_t)M_ROWS*IN_CH*2;
static constexpr size_t B_WB  = B_XB + 3*(size_t)M_ROWS*IN_CH*2;
static constexpr size_t B_WC  = B_WB + 3*(size_t)PS_WB*2;
static constexpr size_t B_WD  = B_WC + 3*(size_t)PS_WC*2;
static constexpr size_t B_LAM = B_WD + 3*(size_t)PS_WD*2;            // lam, lam16
static constexpr size_t B_HC  = B_LAM + 2*768*4;                     // Hc0, Hc1

// ---------------- helpers ----------------
__device__ __forceinline__ u16 f2b(float v) {
    __hip_bfloat16 h = __float2bfloat16(v);
    return *(u16*)&h;
}
__device__ __forceinline__ float b2f(u16 u) {
    __hip_bfloat16 h = *(__hip_bfloat16*)&u;
    return __bfloat162float(h);
}
__device__ __forceinline__ void split3(float v, u16& a, u16& b, u16& c) {
    a = f2b(v);  float r1 = v  - b2f(a);
    b = f2b(r1); float r2 = r1 - b2f(b);
    c = f2b(r2);
}

// A-fragment-ordered (32x32-family) plane index: element (row, k), NKC = K/32.
__device__ __forceinline__ size_t a_idx(int row, int k, int NKC) {
    return ((size_t)(((row >> 5)*NKC + (k >> 5))*2 + ((k >> 4) & 1))*2 + ((k >> 3) & 1))*256
           + (size_t)(row & 31)*8 + (k & 7);
}

// fragment-index decode for weight prep: r -> (t32,h,hi5,lo5,e)
__device__ __forceinline__ void frag_decode(int r, int& t32, int& h, int& hi5,
                                            int& lo5, int& e) {
    t32 = r >> 10; int r2 = r & 1023;
    h = r2 >> 9;   int r3 = r2 & 511;
    hi5 = r3 >> 8; int r4 = r3 & 255;
    lo5 = r4 >> 3; e = r4 & 7;
}

// ---------------- fused prep: lam/hc (extra block) + WB | WC | WD | X --------
__global__ void prep_big(const float* __restrict__ B_re, const float* __restrict__ B_im,
                         const float* __restrict__ gamma_log,
                         const float* __restrict__ C_re, const float* __restrict__ C_im,
                         const float* __restrict__ D, const float* __restrict__ x,
                         const float* __restrict__ nu_log, const float* __restrict__ th_log,
                         u16* __restrict__ W, u16* __restrict__ WC, u16* __restrict__ WD,
                         u16* __restrict__ X1, u16* __restrict__ X2, u16* __restrict__ X3,
                         float* __restrict__ lam, float* __restrict__ lam16,
                         float* __restrict__ hc0) {
    if (blockIdx.x >= 5888) {
        // extra block: lam, lam16 (strided -- 256 threads < STATE=384!), hc0
        for (int n = threadIdx.x; n < STATE; n += blockDim.x) {
            float lm = expf(-expf(nu_log[n]));
            float th = expf(th_log[n]);
            float ar = lm * cosf(th), ai = lm * sinf(th);
            lam[2*n] = ar; lam[2*n+1] = ai;
            float pr = ar, pi = ai;
#pragma unroll
            for (int i = 0; i < 4; ++i) {   // lambda^16
                float nr = pr*pr - pi*pi, ni = 2.f*pr*pi;
                pr = nr; pi = ni;
            }
            lam16[2*n] = pr; lam16[2*n+1] = pi;
        }
        for (int i = threadIdx.x; i < B_SZ*NJ; i += blockDim.x) hc0[i] = 0.f;
        return;
    }
    int idx = blockIdx.x*blockDim.x + threadIdx.x;
    if (idx < PS_WB) {
        int c32 = idx >> 13, r = idx & 8191;
        int t32,h,hi5,lo5,e; frag_decode(r, t32,h,hi5,lo5,e);
        int j = c32*32 + lo5;
        int k = t32*32 + (2*h + hi5)*8 + e;
        int n = j >> 1;
        float g = expf(gamma_log[n]);
        float v = g * ((j & 1) ? B_im[n*IN_CH + k] : B_re[n*IN_CH + k]);
        u16 a,b,cc; split3(v,a,b,cc);
        W[idx] = a; W[idx + PS_WB] = b; W[idx + 2*PS_WB] = cc;
        return;
    }
    idx -= PS_WB;
    if (idx < PS_WC) {
        int c32 = idx / 24576, r = idx % 24576;
        int t32,h,hi5,lo5,e; frag_decode(r, t32,h,hi5,lo5,e);
        int o = c32*32 + lo5;
        int j = t32*32 + (2*h + hi5)*8 + e;
        int n = j >> 1;
        float v = (j & 1) ? -C_im[o*STATE + n] : C_re[o*STATE + n];
        u16 a,b,c; split3(v,a,b,c);
        WC[idx] = a; WC[idx + PS_WC] = b; WC[idx + 2*PS_WC] = c;
        return;
    }
    idx -= PS_WC;
    if (idx < PS_WD) {
        int c32 = idx >> 13, r = idx & 8191;
        int t32,h,hi5,lo5,e; frag_decode(r, t32,h,hi5,lo5,e);
        int o = c32*32 + lo5;
        int c = t32*32 + (2*h + hi5)*8 + e;
        float v = D[o*IN_CH + c];
        u16 a,b,cc; split3(v,a,b,cc);
        WD[idx] = a; WD[idx + PS_WD] = b; WD[idx + 2*PS_WD] = cc;
        return;
    }
    idx -= PS_WD;
    {
        int row = idx >> 8, k = idx & 255;
        u16 a,b,c; split3(x[idx],a,b,c);
        size_t o = a_idx(row, k, 8);
        X1[o] = a; X2[o] = b; X3[o] = c;
    }
}

// product order for bf16x3 (large terms first)
__device__ __constant__ const int cPI[6] = {0,0,1,0,1,2};
__device__ __constant__ const int cPJ[6] = {0,1,0,2,1,0};

// ---------------- FRONT: blocks 0..191: U (LDS) + scan + Z emit; blocks
// 192..255: P = X*WD^T partial (fp32, XCD-aligned rows). 512 threads.
// [R16 structure — known good]
struct G1P { const u16* A[3]; };

__global__ __launch_bounds__(512, 2)
void front_k(G1P ga, const u16* __restrict__ WBp, const u16* __restrict__ WDp,
             u16* __restrict__ Z1, u16* __restrict__ Z2, u16* __restrict__ Z3,
             float* __restrict__ P,
             const float* __restrict__ lam, const float* __restrict__ lam16,
             const float2* __restrict__ HcIn, float2* __restrict__ HcOut) {
    __shared__ __align__(16) float Ls[512*34];     // 69.6KB U tile (front job)
    __shared__ float2 car[32][16];
    __shared__ float2 hp[32][16];
    const int tid = threadIdx.x, lane = tid & 63, w = tid >> 6;
    const int l15 = lane & 15, q = lane >> 4;
    const int hb = q >> 1, hi5q = q & 1;
    const int hi5 = lane >> 5, lo5 = lane & 31;

    if (blockIdx.x >= 192) {
        // ---------- WD job: rows XCD-aligned: mt = (k&7)*8 + (k>>3) ----------
        const int k0 = blockIdx.x - 192;          // 0..63
        const int mt = (k0 & 7)*8 + (k0 >> 3);
        const int wr = w & 1, wc = w >> 1;        // wc 0..3 -> cols wc*64
        const int m32 = mt*2 + wr;
        f32x16 acc[2];
#pragma unroll
        for (int cj = 0; cj < 2; ++cj)
#pragma unroll
            for (int i = 0; i < 16; ++i) acc[cj][i] = 0.f;

        bf16x8 av[2][3][2], bv[2][2][3][2];
        auto loadA = [&](int buf, int kc) {
#pragma unroll
            for (int p = 0; p < 3; ++p)
#pragma unroll
                for (int h = 0; h < 2; ++h)
                    av[buf][p][h] = *(const bf16x8*)(ga.A[p]
                        + ((((size_t)(m32*8 + kc)*2 + h)*2 + hi5) << 8) + lo5*8);
        };
        auto loadB = [&](int buf, int kc) {
#pragma unroll
            for (int cj = 0; cj < 2; ++cj)
#pragma unroll
                for (int p = 0; p < 3; ++p)
#pragma unroll
                    for (int h = 0; h < 2; ++h)
                        bv[buf][cj][p][h] = *(const bf16x8*)(WDp + (size_t)p*PS_WD
                            + ((((size_t)((wc*2 + cj)*8 + kc)*2 + h)*2 + hi5) << 8) + lo5*8);
        };
        loadA(0, 0); loadB(0, 0);
        loadA(1, 1); loadB(1, 1);
#pragma unroll
        for (int kc = 0; kc < 8; ++kc) {
            const int cb = kc & 1;
#pragma unroll
            for (int t6 = 0; t6 < 6; ++t6)
#pragma unroll
                for (int cj = 0; cj < 2; ++cj)
#pragma unroll
                    for (int h = 0; h < 2; ++h)
                        acc[cj] = __builtin_amdgcn_mfma_f32_32x32x16_bf16(
                            av[cb][cPI[t6]][h], bv[cb][cj][cPJ[t6]][h], acc[cj], 0, 0, 0);
            if (kc + 2 < 8) { loadA(cb, kc + 2); loadB(cb, kc + 2); }
        }
#pragma unroll
        for (int cj = 0; cj < 2; ++cj)
#pragma unroll
            for (int reg = 0; reg < 16; ++reg) {
                int row = mt*64 + wr*32 + (reg & 3) + 8*(reg >> 2) + 4*hi5;
                int col = wc*64 + cj*32 + lo5;
                P[(size_t)row*IN_CH + col] = acc[cj][reg];
            }
        return;
    }

    // ---------- front job ----------
    const int b = blockIdx.x & 7, jt = blockIdx.x >> 3;   // XCD-local b

    f32x4 acc[4][2];
#pragma unroll
    for (int i = 0; i < 4; ++i)
#pragma unroll
        for (int n16 = 0; n16 < 2; ++n16) acc[i][n16] = 0.f;

    bf16x8 av[2][4][3], bv[2][2][3];
    auto loadA = [&](int buf, int kc) {
#pragma unroll
        for (int p = 0; p < 3; ++p)
#pragma unroll
            for (int i = 0; i < 4; ++i) {
                int m16 = i*8 + w;
                int row32 = b*16 + (m16 >> 1);
                int rin = ((m16 & 1) << 4) + l15;
                av[buf][i][p] = *(const bf16x8*)(ga.A[p]
                    + ((((size_t)(row32*8 + kc)*2 + hb)*2 + hi5q) << 8) + rin*8);
            }
    };
    auto loadB = [&](int buf, int kc) {
#pragma unroll
        for (int p = 0; p < 3; ++p)
#pragma unroll
            for (int n16 = 0; n16 < 2; ++n16)
                bv[buf][n16][p] = *(const bf16x8*)(WBp + (size_t)p*PS_WB
                    + ((((size_t)(jt*8 + kc)*2 + hb)*2 + hi5q) << 8) + (n16*16 + l15)*8);
    };

    loadA(0, 0); loadB(0, 0);
    loadA(1, 1); loadB(1, 1);
#pragma unroll
    for (int kc = 0; kc < 8; ++kc) {
        const int cb = kc & 1;
#pragma unroll
        for (int t6 = 0; t6 < 6; ++t6)
#pragma unroll
            for (int i = 0; i < 4; ++i)
#pragma unroll
                for (int n16 = 0; n16 < 2; ++n16)
                    acc[i][n16] = __builtin_amdgcn_mfma_f32_16x16x32_bf16(
                        av[cb][i][cPI[t6]], bv[cb][n16][cPJ[t6]], acc[i][n16], 0, 0, 0);
        if (kc + 2 < 8) { loadA(cb, kc + 2); loadB(cb, kc + 2); }
    }

    // deposit U tile to LDS. D-layout (16x16): col=l15, row=q*4+r
#pragma unroll
    for (int i = 0; i < 4; ++i) {
        int m16 = i*8 + w;
#pragma unroll
        for (int n16 = 0; n16 < 2; ++n16)
#pragma unroll
            for (int r = 0; r < 4; ++r) {
                int s = m16*16 + q*4 + r;
                int jl = n16*16 + l15;
                Ls[s*34 + jl] = acc[i][n16][r];
            }
    }
    __syncthreads();

    // pass 1: chunk-local scan from 0; stores local h IN PLACE (over u)
    {
        int st = tid & 15, ch = tid >> 4;
        int n = jt*16 + st;
        float lre = lam[2*n], lim = lam[2*n+1];
        float hr = 0.f, hm = 0.f;
#pragma unroll
        for (int t = 0; t < 16; ++t) {
            int s = ch*16 + t;
            float2 u = *(const float2*)&Ls[s*34 + 2*st];
            float nr = fmaf(lre, hr, fmaf(-lim, hm, u.x));
            float nm = fmaf(lre, hm, fmaf( lim, hr, u.y));
            hr = nr; hm = nm;
            *(float2*)&Ls[s*34 + 2*st] = make_float2(hr, hm);
        }
        car[ch][st] = make_float2(hr, hm);
    }
    __syncthreads();

    // parallel prefix over 32 chunks (complex affine maps), all waves.
    {
        int st2 = 2*w + hi5, ch2 = lane & 31;
        int n = jt*16 + st2;
        float2 e = car[ch2][st2];
        float Ar = lam16[2*n], Ai = lam16[2*n+1];
        float Br = e.x, Bi = e.y;
#pragma unroll
        for (int d = 1; d < 32; d <<= 1) {
            int src = (lane & 32) | ((lane - d) & 31);
            float pAr = __shfl(Ar, src), pAi = __shfl(Ai, src);
            float pBr = __shfl(Br, src), pBi = __shfl(Bi, src);
            if (ch2 >= d) {
                float nAr = Ar*pAr - Ai*pAi;
                float nAi = Ar*pAi + Ai*pAr;
                float nBr = fmaf(Ar, pBr, fmaf(-Ai, pBi, Br));
                float nBi = fmaf(Ar, pBi, fmaf( Ai, pBr, Bi));
                Ar = nAr; Ai = nAi; Br = nBr; Bi = nBi;
            }
        }
        float2 s0 = HcIn[(size_t)b*STATE + n];
        if (ch2 == 31) {
            float fr = fmaf(Ar, s0.x, fmaf(-Ai, s0.y, Br));
            float fi = fmaf(Ar, s0.y, fmaf( Ai, s0.x, Bi));
            HcOut[(size_t)b*STATE + n] = make_float2(fr, fi);
        }
        int srcp = (lane & 32) | ((lane - 1) & 31);
        float eAr = __shfl(Ar, srcp), eAi = __shfl(Ai, srcp);
        float eBr = __shfl(Br, srcp), eBi = __shfl(Bi, srcp);
        float sr, si;
        if (ch2 == 0) { sr = s0.x; si = s0.y; }
        else {
            sr = fmaf(eAr, s0.x, fmaf(-eAi, s0.y, eBr));
            si = fmaf(eAr, s0.y, fmaf( eAi, s0.x, eBi));
        }
        hp[ch2][st2] = make_float2(sr, si);
    }
    __syncthreads();

    // pass 2: elementwise h_t = local_t + lambda^{t+1}*hp; split3; emit
    {
        int st = tid & 15, ch = tid >> 4;
        int n = jt*16 + st;
        float lre = lam[2*n], lim = lam[2*n+1];
        float2 hh = hp[ch][st];
        float lpr = lre, lpi = lim;                 // lambda^{1}
        int j0 = jt*32 + 2*st;
#pragma unroll
        for (int t = 0; t < 16; ++t) {
            int s = ch*16 + t;
            float2 hl = *(const float2*)&Ls[s*34 + 2*st];
            float vr = fmaf(lpr, hh.x, fmaf(-lpi, hh.y, hl.x));
            float vi = fmaf(lpr, hh.y, fmaf( lpi, hh.x, hl.y));
            float nlr = lpr*lre - lpi*lim;
            float nli = lpr*lim + lpi*lre;
            lpr = nlr; lpi = nli;
            u16 a1,a2,a3, c1,c2,c3;
            split3(vr, a1,a2,a3);
            split3(vi, c1,c2,c3);
            size_t zo = a_idx(b*512 + s, j0, 24);
            ushort2 t2;
            t2.x = a1; t2.y = c1; *(ushort2*)(Z1 + zo) = t2;
            t2.x = a2; t2.y = c2; *(ushort2*)(Z2 + zo) = t2;
            t2.x = a3; t2.y = c3; *(ushort2*)(Z3 + zo) = t2;
        }
    }
}

// ---------------- GEMM2: Z*WC^T (K=768) + Lred + P; grid 256 XCD-aligned,
// 768 threads = 12 waves: kg(3-way K split, 8 chunks) x wr(2) x wcq(2).
// A-prefetch 3-deep, B 2-deep.
struct G2P {
    const u16* Z[3]; const u16* WC; const float* P;
    u16* O1; u16* O2; u16* O3; float* outp; int iter;
};

__global__ __launch_bounds__(768, 3)
void gemm2_k(G2P g) {
    __shared__ __align__(16) float Lred[2*4*1024];  // 32KB: [kg-1][wr*2+wcq][32*32]
    const int tid = threadIdx.x, lane = tid & 63, w = tid >> 6;   // w 0..11
    const int kg = w >> 2, wq = w & 3;
    const int wr = wq & 1, wcq = wq >> 1;
    const int bid = blockIdx.x;
    const int b = bid & 7, mloc = (bid >> 3) & 7, n_t = bid >> 6;
    const int mtile = b*8 + mloc;
    const int m0 = mtile*64, n0 = n_t*64;
    const int hi5 = lane >> 5, lo5 = lane & 31;
    const int c32 = n_t*2 + wcq;
    const int m32 = mtile*2 + wr;
    const int cbase = kg*8;

    f32x16 accv;
#pragma unroll
    for (int i = 0; i < 16; ++i) accv[i] = 0.f;

    auto aptr = [&](int p, int c, int h) -> const u16* {
        return g.Z[p] + ((((size_t)(m32*24 + c)*2 + h)*2 + hi5) << 8) + lo5*8;
    };
    auto bptr = [&](int p, int c, int h) -> const u16* {
        return g.WC + (size_t)p*PS_WC
               + ((((size_t)(c32*24 + c)*2 + h)*2 + hi5) << 8) + lo5*8;
    };

    bf16x8 av[3][3][2], bv[2][3][2];
    auto loadA = [&](int buf, int t) {
#pragma unroll
        for (int p = 0; p < 3; ++p)
#pragma unroll
            for (int h = 0; h < 2; ++h)
                av[buf][p][h] = *(const bf16x8*)aptr(p, cbase + t, h);
    };
    auto loadB = [&](int buf, int t) {
#pragma unroll
        for (int p = 0; p < 3; ++p)
#pragma unroll
            for (int h = 0; h < 2; ++h)
                bv[buf][p][h] = *(const bf16x8*)bptr(p, cbase + t, h);
    };

    loadA(0, 0); loadB(0, 0);
    loadA(1, 1); loadB(1, 1);
    loadA(2, 2);
#pragma unroll
    for (int t = 0; t < 8; ++t) {
        const int ca = t % 3;
        const int cb = t & 1;
#pragma unroll
        for (int t6 = 0; t6 < 6; ++t6)
            accv = __builtin_amdgcn_mfma_f32_32x32x16_bf16(
                av[ca][cPI[t6]][0], bv[cb][cPJ[t6]][0],
                __builtin_amdgcn_mfma_f32_32x32x16_bf16(
                    av[ca][cPI[t6]][1], bv[cb][cPJ[t6]][1], accv, 0, 0, 0),
                0, 0, 0);
        if (t + 3 < 8) loadA(ca, t + 3);
        if (t + 2 < 8) loadB(cb, t + 2);
    }

    // kg=1,2 waves deposit partials; kg=0 waves sum + P + epilogue
    if (kg != 0) {
        float* Lp = Lred + ((size_t)(kg - 1)*4 + wr*2 + wcq)*1024;
#pragma unroll
        for (int reg = 0; reg < 16; ++reg) {
            int rl = (reg & 3) + 8*(reg >> 2) + 4*hi5;
            Lp[rl*32 + lo5] = accv[reg];
        }
    }
    __syncthreads();
    if (kg == 0) {
        const float* L1 = Lred + ((size_t)0*4 + wr*2 + wcq)*1024;
        const float* L2 = Lred + ((size_t)1*4 + wr*2 + wcq)*1024;
#pragma unroll
        for (int reg = 0; reg < 16; ++reg) {
            int rl = (reg & 3) + 8*(reg >> 2) + 4*hi5;
            int row = m0 + wr*32 + rl;
            int col = n0 + wcq*32 + lo5;
            float v = accv[reg] + L1[rl*32 + lo5] + L2[rl*32 + lo5]
                    + g.P[(size_t)row*IN_CH + col];
            u16 a,b2,c; split3(v, a,b2,c);
            size_t o = a_idx(row, col, 8);
            g.O1[o] = a; g.O2[o] = b2; g.O3[o] = c;
            if ((row & (SEQ-1)) == SEQ-1)
                g.outp[(size_t)((row >> 9)*OUT_SEQ + g.iter)*IN_CH + col] = v;
        }
    }
}

// ---------------- launch ----------------
extern "C" void kernel_launch(void* const* d_in, const int* in_sizes, int n_in,
                              void* d_out, int out_size, void* d_ws, size_t ws_size,
                              hipStream_t stream) {
    const float* x_in      = (const float*)d_in[0];
    const float* nu_log    = (const float*)d_in[1];
    const float* theta_log = (const float*)d_in[2];
    const float* gamma_log = (const float*)d_in[3];
    const float* B_re      = (const float*)d_in[4];
    const float* B_im      = (const float*)d_in[5];
    const float* C_re      = (const float*)d_in[6];
    const float* C_im      = (const float*)d_in[7];
    const float* D         = (const float*)d_in[8];
    float* out = (float*)d_out;

    char* ws = (char*)d_ws;
    float* P = (float*)(ws + B_U);                 // [4096][256] fp32 partial
    u16* Z1 = (u16*)(ws + B_Z);
    u16* Z2 = Z1 + PS_Z;
    u16* Z3 = Z2 + PS_Z;
    u16* XA1 = (u16*)(ws + B_XA);
    u16* XA2 = XA1 + PS_X;
    u16* XA3 = XA2 + PS_X;
    u16* XB1 = (u16*)(ws + B_XB);
    u16* XB2 = XB1 + PS_X;
    u16* XB3 = XB2 + PS_X;
    u16* WB  = (u16*)(ws + B_WB);
    u16* WCt = (u16*)(ws + B_WC);
    u16* WDt = (u16*)(ws + B_WD);
    float* lam   = (float*)(ws + B_LAM);
    float* lam16 = lam + 768;
    float2* Hc0  = (float2*)(ws + B_HC);
    float2* Hc1  = Hc0 + (size_t)B_SZ*STATE;

    prep_big<<<5889, 256, 0, stream>>>(B_re, B_im, gamma_log, C_re, C_im, D, x_in,
                                       nu_log, theta_log,
                                       WB, WCt, WDt, XA1, XA2, XA3,
                                       lam, lam16, (float*)Hc0);

    for (int it = 0; it < OUT_SEQ; ++it) {
        u16* Xc[3]; u16* Xn[3];
        if (it & 1) { Xc[0]=XB1; Xc[1]=XB2; Xc[2]=XB3; Xn[0]=XA1; Xn[1]=XA2; Xn[2]=XA3; }
        else        { Xc[0]=XA1; Xc[1]=XA2; Xc[2]=XA3; Xn[0]=XB1; Xn[1]=XB2; Xn[2]=XB3; }
        float2* Hin  = (it & 1) ? Hc1 : Hc0;
        float2* Hout = (it & 1) ? Hc0 : Hc1;

        // FRONT: U+scan+Z emit (192 blocks) and P = X*WD^T (64 blocks)
        G1P g1;
        for (int p = 0; p < 3; ++p) g1.A[p] = Xc[p];
        front_k<<<256, 512, 0, stream>>>(
            g1, WB, WDt, Z1, Z2, Z3, P, lam, lam16, Hin, Hout);

        // GEMM2: Z*WC^T (K=768) + Lred + P -> Xn frags + out (12 waves, 3-deep A)
        G2P g2;
        g2.Z[0]=Z1; g2.Z[1]=Z2; g2.Z[2]=Z3;
        g2.WC = WCt; g2.P = P;
        g2.O1 = Xn[0]; g2.O2 = Xn[1]; g2.O3 = Xn[2];
        g2.outp = out; g2.iter = it;
        gemm2_k<<<256, 768, 0, stream>>>(g2);
    }
}